// Round 8
// baseline (651.228 us; speedup 1.0000x reference)
//
#include <hip/hip_runtime.h>
#include <math.h>

#define NN 2048
#define NM1 2047
#define EDGES (NN * NM1)      // 4,192,256
#define KORD 8
#define NHEADS 4
#define BETA 0.5f
#define EPSV 1e-6f
#define NT 32                 // K-tiles of 64

typedef __attribute__((ext_vector_type(8))) short bf16x8;
typedef __attribute__((ext_vector_type(4))) float f32x4;

__device__ __forceinline__ unsigned short f2bf(float f) {
    unsigned u = __builtin_bit_cast(unsigned, f);
    u += 0x7FFF + ((u >> 16) & 1);          // round-to-nearest-even
    return (unsigned short)(u >> 16);
}
__device__ __forceinline__ float bf2f(unsigned short h) {
    unsigned u = ((unsigned)h) << 16;
    return __builtin_bit_cast(float, u);
}

#define GLD16(gp, lp) __builtin_amdgcn_global_load_lds(                         \
    (const __attribute__((address_space(1))) void*)(gp),                        \
    (__attribute__((address_space(3))) void*)(lp), 16, 0, 0)

// ---------------- kernel 1: edge softmax (runs LAST; writes final edge_prob) ----------------
__global__ void k_prob(const float* __restrict__ logits, float* __restrict__ out) {
    int e = blockIdx.x * 256 + threadIdx.x;
    if (e >= EDGES) return;
    float l0 = logits[e];
    float l1 = logits[EDGES + e];
    float p0 = 1.f / (1.f + __expf(BETA * (l1 - l0)));
    float p1 = 1.f / (1.f + __expf(BETA * (l0 - l1)));
    out[e]         = p0;
    out[EDGES + e] = p1;
}

// ---------------- kernel 2: row sums from logits -> dinv[2][NN] ----------------
__global__ __launch_bounds__(256) void k_dinv(const float* __restrict__ logits, float* __restrict__ dinv) {
    int row = blockIdx.x;
    const float* r0 = logits + (size_t)row * NM1;
    const float* r1 = r0 + EDGES;
    float s = 0.f;
    for (int t = threadIdx.x; t < NM1; t += 256) {
        float l0 = r0[t], l1 = r1[t];
        s += 1.f / (1.f + __expf(BETA * (l1 - l0)));
    }
    for (int off = 32; off; off >>= 1) s += __shfl_down(s, off);
    __shared__ float red[4];
    if ((threadIdx.x & 63) == 0) red[threadIdx.x >> 6] = s;
    __syncthreads();
    if (threadIdx.x == 0) {
        float s0 = red[0] + red[1] + red[2] + red[3];
        dinv[row]      = 1.f / sqrtf(s0 + EPSV);
        dinv[NN + row] = 1.f / sqrtf((float)NM1 - s0 + EPSV);
    }
}

// ---------------- kernel 3: Lb = bf16(-dinv_i * p * dinv_j), diag 0, both branches ----------------
__global__ __launch_bounds__(256) void k_build(const float* __restrict__ logits, const float* __restrict__ dinv,
                                               unsigned short* __restrict__ Lb0, unsigned short* __restrict__ Lb1) {
    int idx = blockIdx.x * 256 + threadIdx.x;   // over N*N
    int i = idx >> 11, j = idx & (NN - 1);
    float v0 = 0.f, v1 = 0.f;
    if (i != j) {
        size_t e = (size_t)i * NM1 + (j < i ? j : j - 1);
        float l0 = logits[e], l1 = logits[EDGES + e];
        float p0 = 1.f / (1.f + __expf(BETA * (l1 - l0)));
        v0 = -dinv[i] * p0 * dinv[j];
        v1 = -dinv[NN + i] * (1.f - p0) * dinv[NN + j];
    }
    Lb0[idx] = f2bf(v0);
    Lb1[idx] = f2bf(v1);
}

// ---------------- kernel 4: 64x64 bf16 transpose (dual-branch) ----------------
__global__ __launch_bounds__(256) void k_transpose(
    const unsigned short* __restrict__ S0, const unsigned short* __restrict__ S1,
    unsigned short* __restrict__ D0, unsigned short* __restrict__ D1) {
    __shared__ unsigned short T[64 * 66];
    const unsigned short* S = blockIdx.z ? S1 : S0;
    unsigned short* D = blockIdx.z ? D1 : D0;
    int t = threadIdx.x;
    int I0 = blockIdx.y * 64, J0 = blockIdx.x * 64;
    int r = t >> 2, cb = (t & 3) * 16;
    {
        const uint4* src = (const uint4*)(S + (size_t)(I0 + r) * NN + J0 + cb);
        uint4 v0 = src[0], v1 = src[1];
        unsigned* d = (unsigned*)&T[r * 66 + cb];
        d[0] = v0.x; d[1] = v0.y; d[2] = v0.z; d[3] = v0.w;
        d[4] = v1.x; d[5] = v1.y; d[6] = v1.z; d[7] = v1.w;
    }
    __syncthreads();
    union { unsigned short u[16]; uint4 q[2]; } pk;
#pragma unroll
    for (int q = 0; q < 16; ++q) pk.u[q] = T[(cb + q) * 66 + r];
    unsigned short* dst = D + (size_t)(J0 + r) * NN + I0 + cb;
    ((uint4*)dst)[0] = pk.q[0];
    ((uint4*)dst)[1] = pk.q[1];
}

// ---------------- 256x256 8-wave 4-phase/K-tile MFMA core ----------------
// O = 2*(A @ BT^T) - (first ? I : Um2).  BK=64 staged as K-half slots [256][32],
// 4 slots per operand (slot = g&3, g = K-half index = 2t+kk).  Counted vmcnt(4)
// once per K-tile; lgkmcnt(0)+sched_barrier before MFMA (rule 18); setprio (T5).
__device__ __forceinline__ void gemm256_core(
    const unsigned short* __restrict__ A, const unsigned short* __restrict__ BT,
    const unsigned short* __restrict__ Um2, unsigned short* __restrict__ Un,
    int first, int r0, int c0) {
    __shared__ unsigned short Als[4][256 * 32];   // 64 KiB
    __shared__ unsigned short Bls[4][256 * 32];   // 64 KiB
    unsigned short* Af = &Als[0][0];
    unsigned short* Bf = &Bls[0][0];

    int tid = threadIdx.x;
    int w = tid >> 6, l = tid & 63;
    int wr = w >> 2, wcn = w & 3;          // 2x4 wave grid; wave owns 128x64 of C
    int lr = l & 15, lq = l >> 4;

    // ---- staging precompute: per thread one 16B chunk per issue ----
    // issue i covers local rows i*128 + (tid>>2); stored chunk tid&3 sources
    // global chunk (tid&3) ^ key, key = ((row mod 16)>>1)&3 (row mod 16 == (tid>>2) mod 16)
    int srow = tid >> 2;                   // 0..127
    int key  = (srow >> 1) & 3;
    int swzc = ((tid & 3) ^ key) << 3;
    const unsigned short* pa = A  + (size_t)(r0 + srow) * NN + swzc;
    const unsigned short* pb = BT + (size_t)(c0 + srow) * NN + swzc;
    const int ldst = w << 9;               // wave-uniform LDS offset (elements)

    auto stgA = [&](int slot, int g) {
        const unsigned short* s = pa + g * 32;
        unsigned short* d = Af + slot * 8192 + ldst;
        GLD16(s, d);
        GLD16(s + (size_t)128 * NN, d + 4096);
    };
    auto stgB = [&](int slot, int g) {
        const unsigned short* s = pb + g * 32;
        unsigned short* d = Bf + slot * 8192 + ldst;
        GLD16(s, d);
        GLD16(s + (size_t)128 * NN, d + 4096);
    };

    // ---- frag read precompute (read side uses the same XOR key on (row mod 16)>>1) ----
    int rchk = (lq ^ ((lr >> 1) & 3)) << 3;
    const int aoff = (wr * 128 + lr) * 32 + rchk;
    const int boff = (wcn * 64 + lr) * 32 + rchk;

    f32x4 acc[8][4] = {};
    bf16x8 bfr[4];

#define VMC4 asm volatile("s_waitcnt vmcnt(4)" ::: "memory")
#define VMC0 asm volatile("s_waitcnt vmcnt(0)" ::: "memory")

#define PHASE(slotA, slotB, M0, READB, STAGE_STMT, VM_STMT) do {                \
        bf16x8 afr[4];                                                          \
        _Pragma("unroll")                                                       \
        for (int mm = 0; mm < 4; ++mm)                                          \
            afr[mm] = *(const bf16x8*)(Af + (slotA) * 8192 + aoff + ((M0) + mm) * 512); \
        if (READB) {                                                            \
            _Pragma("unroll")                                                   \
            for (int n = 0; n < 4; ++n)                                         \
                bfr[n] = *(const bf16x8*)(Bf + (slotB) * 8192 + boff + n * 512); \
        }                                                                       \
        STAGE_STMT;                                                             \
        VM_STMT;                                                                \
        __builtin_amdgcn_s_barrier();                                           \
        asm volatile("s_waitcnt lgkmcnt(0)" ::: "memory");                      \
        __builtin_amdgcn_sched_barrier(0);                                      \
        __builtin_amdgcn_s_setprio(1);                                          \
        _Pragma("unroll")                                                       \
        for (int mm = 0; mm < 4; ++mm)                                          \
            _Pragma("unroll")                                                   \
            for (int n = 0; n < 4; ++n)                                         \
                acc[(M0) + mm][n] = __builtin_amdgcn_mfma_f32_16x16x32_bf16(    \
                    afr[mm], bfr[n], acc[(M0) + mm][n], 0, 0, 0);               \
        __builtin_amdgcn_s_setprio(0);                                          \
        __builtin_amdgcn_s_barrier();                                           \
        __builtin_amdgcn_sched_barrier(0);                                      \
    } while (0)

    // ---- prologue: stage g=0..3 both operands except A(3) (staged at t=0 p0) ----
    stgB(0, 0); stgA(0, 0); stgB(1, 1); stgA(1, 1);
    stgB(2, 2); stgA(2, 2); stgB(3, 3);
    VMC0;
    __builtin_amdgcn_s_barrier();
    __builtin_amdgcn_sched_barrier(0);

    for (int t = 0; t < NT; ++t) {
        int s0 = (t & 1) << 1, s1 = s0 + 1;
        // p0: kk0 m0-3 (+B kk0); stage A(2t+3); vmcnt
        if (t + 1 < NT) {
            PHASE(s0, s0, 0, 1, stgA((2 * t + 3) & 3, 2 * t + 3), VMC4);
        } else {
            PHASE(s0, s0, 0, 1, (void)0, VMC0);
        }
        // p1: kk0 m4-7; stage B(2t+4)
        PHASE(s0, s0, 4, 0, if (t + 2 < NT) stgB((2 * t + 4) & 3, 2 * t + 4), (void)0);
        // p2: kk1 m0-3 (+B kk1); stage A(2t+4)
        PHASE(s1, s1, 0, 1, if (t + 2 < NT) stgA((2 * t + 4) & 3, 2 * t + 4), (void)0);
        // p3: kk1 m4-7; stage B(2t+5)
        PHASE(s1, s1, 4, 0, if (t + 2 < NT) stgB((2 * t + 5) & 3, 2 * t + 5), (void)0);
    }
#undef PHASE
#undef VMC4
#undef VMC0

    // ---- epilogue: C/D layout col = lr, row = lq*4 + rr (m89) ----
#pragma unroll
    for (int m = 0; m < 8; ++m)
#pragma unroll
        for (int n = 0; n < 4; ++n)
#pragma unroll
            for (int rr = 0; rr < 4; ++rr) {
                int row = r0 + wr * 128 + m * 16 + lq * 4 + rr;
                int col = c0 + wcn * 64 + n * 16 + lr;
                size_t off = (size_t)row * NN + col;
                float prev = first ? (row == col ? 1.f : 0.f) : bf2f(Um2[off]);
                Un[off] = f2bf(2.f * acc[m][n][rr] - prev);
            }
}

// GEMM1: U2 = 2*(LT @ Lb^T) - I, dual-branch, grid (8,8,2), 512 thr
__global__ __launch_bounds__(512, 2) void k_cheb1(
    const unsigned short* __restrict__ LT0, const unsigned short* __restrict__ LT1,
    const unsigned short* __restrict__ Lb0, const unsigned short* __restrict__ Lb1) {
    int z = blockIdx.z;
    // outputs passed via globals? no — wire directly: computed below in launcher via params
    // (placeholder; real signature in k_cheb1_full)
}

// Full-signature variants (outputs as args)
__global__ __launch_bounds__(512, 2) void k_cheb256_1(
    const unsigned short* __restrict__ A0, const unsigned short* __restrict__ A1,
    const unsigned short* __restrict__ B0, const unsigned short* __restrict__ B1,
    unsigned short* __restrict__ O0, unsigned short* __restrict__ O1) {
    int z = blockIdx.z;
    gemm256_core(z ? A1 : A0, z ? B1 : B0, z ? A1 : A0, z ? O1 : O0, 1,
                 blockIdx.y * 256, blockIdx.x * 256);
}

// Pair GEMM: grid (8,16,2): y&7 = row-tile, y>>3 = half (lo/hi operand set)
__global__ __launch_bounds__(512, 2) void k_cheb256_p(
    const unsigned short* __restrict__ Alo0, const unsigned short* __restrict__ Ahi0,
    const unsigned short* __restrict__ Alo1, const unsigned short* __restrict__ Ahi1,
    const unsigned short* __restrict__ BT0,  const unsigned short* __restrict__ BT1,
    const unsigned short* __restrict__ Plo0, const unsigned short* __restrict__ Phi0,
    const unsigned short* __restrict__ Plo1, const unsigned short* __restrict__ Phi1,
    unsigned short* __restrict__ Olo0, unsigned short* __restrict__ Ohi0,
    unsigned short* __restrict__ Olo1, unsigned short* __restrict__ Ohi1,
    int firstlo, int firsthi) {
    int z = blockIdx.z;
    int half = blockIdx.y >> 3, my = blockIdx.y & 7;
    const unsigned short* A  = z ? (half ? Ahi1 : Alo1) : (half ? Ahi0 : Alo0);
    const unsigned short* BT = z ? BT1 : BT0;
    const unsigned short* P  = z ? (half ? Phi1 : Plo1) : (half ? Phi0 : Plo0);
    unsigned short* O        = z ? (half ? Ohi1 : Olo1) : (half ? Ohi0 : Olo0);
    gemm256_core(A, BT, P, O, half ? firsthi : firstlo, my * 256, blockIdx.x * 256);
}

// ---------------- kernel 6: fused gather + head projection ----------------
// t_k[i][j] = U_k[j][i] for ALL k (M1 = LT = U_1).  f_h = b_h + sum_k w[h][k-1]*t_k
__global__ __launch_bounds__(256) void k_gather(
    const unsigned short* __restrict__ M1, const unsigned short* __restrict__ M2,
    const unsigned short* __restrict__ M3, const unsigned short* __restrict__ M4,
    const unsigned short* __restrict__ M5, const unsigned short* __restrict__ M6,
    const unsigned short* __restrict__ M7, const unsigned short* __restrict__ M8,
    const float* __restrict__ w, const float* __restrict__ bias,
    float* __restrict__ fout) {
    __shared__ unsigned short G[64 * 66];
    int t = threadIdx.x;
    int I0 = blockIdx.y * 64, J0 = blockIdx.x * 64;
    int jo = t & 63, ig = t >> 6;
    int sr = t >> 2, scb = (t & 3) * 16;

    float acc[4][16];
#pragma unroll
    for (int h = 0; h < 4; ++h)
#pragma unroll
        for (int s = 0; s < 16; ++s) acc[h][s] = 0.f;

    const unsigned short* mats[8] = {M1, M2, M3, M4, M5, M6, M7, M8};
#pragma unroll
    for (int kk = 0; kk < 8; ++kk) {
        const unsigned short* M = mats[kk];
        __syncthreads();
        {
            const uint4* src = (const uint4*)(M + (size_t)(J0 + sr) * NN + I0 + scb);
            uint4 v0 = src[0], v1 = src[1];
            unsigned* d = (unsigned*)&G[sr * 66 + scb];
            d[0] = v0.x; d[1] = v0.y; d[2] = v0.z; d[3] = v0.w;
            d[4] = v1.x; d[5] = v1.y; d[6] = v1.z; d[7] = v1.w;
        }
        __syncthreads();
        float c0w = w[0 * KORD + kk], c1w = w[1 * KORD + kk];
        float c2w = w[2 * KORD + kk], c3w = w[3 * KORD + kk];
#pragma unroll
        for (int s = 0; s < 16; ++s) {
            int io = ig * 16 + s;
            float v = bf2f(G[jo * 66 + io]);
            acc[0][s] += c0w * v;
            acc[1][s] += c1w * v;
            acc[2][s] += c2w * v;
            acc[3][s] += c3w * v;
        }
    }
    float b0v = bias[0], b1v = bias[1], b2v = bias[2], b3v = bias[3];
#pragma unroll
    for (int s = 0; s < 16; ++s) {
        int i = I0 + ig * 16 + s;
        int j = J0 + jo;
        if (i == j) continue;
        size_t e = (size_t)i * NM1 + (j < i ? j : j - 1);
        fout[0 * (size_t)EDGES + e] = b0v + acc[0][s];
        fout[1 * (size_t)EDGES + e] = b1v + acc[1][s];
        fout[2 * (size_t)EDGES + e] = b2v + acc[2][s];
        fout[3 * (size_t)EDGES + e] = b3v + acc[3][s];
    }
}

extern "C" void kernel_launch(void* const* d_in, const int* in_sizes, int n_in,
                              void* d_out, int out_size, void* d_ws, size_t ws_size,
                              hipStream_t stream) {
    const float* logits = (const float*)d_in[1];
    const float* w0 = (const float*)d_in[2];
    const float* b0 = (const float*)d_in[3];
    const float* w1 = (const float*)d_in[4];
    const float* b1 = (const float*)d_in[5];
    float* out = (float*)d_out;

    const size_t MATB = (size_t)NN * NN * sizeof(unsigned short);   // 8 MiB
    // branch-0 slots in ws: [0]=Lb0 (V2_0 after), [1]=LT0, [2..8]=U0[2..8]  (75.5 MiB)
    char* ws = (char*)d_ws;
    unsigned short* s0[9];
    for (int k = 0; k < 9; ++k) s0[k] = (unsigned short*)(ws + (size_t)k * MATB);
    float* dinv = (float*)(ws + 9 * MATB);
    // branch-1 slots in d_out [0, 75.5 MiB) — f1 (written by b1-gather) starts at 100.6 MiB;
    // f0 and edge_prob regions are rewritten AFTER branch-1 scratch is dead.
    char* ob = (char*)d_out;
    unsigned short* s1[9];
    for (int k = 0; k < 9; ++k) s1[k] = (unsigned short*)(ob + (size_t)k * MATB);

    k_dinv<<<NN, 256, 0, stream>>>(logits, dinv);
    k_build<<<(NN * NN) / 256, 256, 0, stream>>>(logits, dinv, s0[0], s1[0]);
    k_transpose<<<dim3(32, 32, 2), 256, 0, stream>>>(s0[0], s1[0], s0[1], s1[1]);  // Lb -> LT

    // U2 = 2*(U1 @ L^T) - I
    k_cheb256_1<<<dim3(8, 8, 2), 512, 0, stream>>>(s0[1], s1[1], s0[0], s1[0], s0[2], s1[2]);
    // V2 = U2^T, overwrites Lb (dead after GEMM1)
    k_transpose<<<dim3(32, 32, 2), 256, 0, stream>>>(s0[2], s1[2], s0[0], s1[0]);

    // pair1: U3 = 2*U1@U2 - U1 (A=LT,P=LT) ; U4 = 2*U2@U2 - I (A=U2, first)
    k_cheb256_p<<<dim3(8, 16, 2), 512, 0, stream>>>(
        s0[1], s0[2], s1[1], s1[2], s0[0], s1[0],
        s0[1], s0[2], s1[1], s1[2],            // Phi = dummy (firsthi=1)
        s0[3], s0[4], s1[3], s1[4], 0, 1);
    // pair2: U5 = 2*U3@U2 - U1 ; U6 = 2*U4@U2 - U2
    k_cheb256_p<<<dim3(8, 16, 2), 512, 0, stream>>>(
        s0[3], s0[4], s1[3], s1[4], s0[0], s1[0],
        s0[1], s0[2], s1[1], s1[2],
        s0[5], s0[6], s1[5], s1[6], 0, 0);
    // pair3: U7 = 2*U5@U2 - U3 ; U8 = 2*U6@U2 - U4
    k_cheb256_p<<<dim3(8, 16, 2), 512, 0, stream>>>(
        s0[5], s0[6], s1[5], s1[6], s0[0], s1[0],
        s0[3], s0[4], s1[3], s1[4],
        s0[7], s0[8], s1[7], s1[8], 0, 0);

    // gathers: branch 1 first (its scratch lives below f0/edge regions written later)
    float* f1 = out + 6 * (size_t)EDGES;
    k_gather<<<dim3(32, 32), 256, 0, stream>>>(s1[1], s1[2], s1[3], s1[4], s1[5], s1[6], s1[7], s1[8],
                                               w1, b1, f1);
    float* f0 = out + 2 * (size_t)EDGES;
    k_gather<<<dim3(32, 32), 256, 0, stream>>>(s0[1], s0[2], s0[3], s0[4], s0[5], s0[6], s0[7], s0[8],
                                               w0, b0, f0);
    // edge_prob last (branch-1 scratch overlapped this region)
    k_prob<<<(EDGES + 255) / 256, 256, 0, stream>>>(logits, out);
}